// Round 3
// baseline (326.942 us; speedup 1.0000x reference)
//
#include <hip/hip_runtime.h>

#define MARGIN 0.2f
#define LAMBDA_CONSISTENCY 0.1f
#define COS_EPS 1e-8f

// ---------------------------------------------------------------------------
// Fused pass, software-pipelined. Each block owns a contiguous chunk of rows.
// Per row k (double-buffered red[], single 32KB staging buffer, 2 barriers):
//   stage a(k) [prefetched regs] -> LDS
//   issue loads of row ha[k]                (consumed after gather)
//   sync1
//   issue prefetch loads of row k+1         (consumed at next staging)
//   gather: dot_col/colsq from LDS (own cols via ds_read_b128, ht via gather)
//   row-dot d = v . b(ha row), rowsq s = v . v ; wave-reduce -> red[k&1]
//   sync2 ; t0 writes dot_row[k], rowsq[k]
// S is read from HBM once coalesced + once for ha-rows (partially L3-hit).
// ---------------------------------------------------------------------------
__global__ __launch_bounds__(1024, 8) void fused_pass_kernel(
    const float* __restrict__ S, const int* __restrict__ ha,
    const int* __restrict__ ht,
    float* __restrict__ dot_col, float* __restrict__ colsq,
    float* __restrict__ dot_row, float* __restrict__ rowsq,
    int B, int rows_per_block) {
  extern __shared__ float lds[];  // B floats staging + 64 reduction slots
  float* red = lds + B;           // red[2][2][16]
  float4* lds4 = (float4*)lds;
  const int t = threadIdx.x;

  // column ownership matches staging layout: cols 4t..4t+3 and 4096+4t..+3
  int4 h0 = ((const int4*)ht)[t];
  int4 h1 = ((const int4*)ht)[t + 1024];
  const int hti[8] = {h0.x, h0.y, h0.z, h0.w, h1.x, h1.y, h1.z, h1.w};

  float dacc[8], sacc[8];
#pragma unroll
  for (int c = 0; c < 8; ++c) { dacc[c] = 0.f; sacc[c] = 0.f; }

  const int k0 = blockIdx.x * rows_per_block;
  const int kend = k0 + rows_per_block;

  // prologue: prefetch row k0 and ha[k0]
  const float4* rp = (const float4*)(S + (size_t)k0 * B);
  float4 a0 = rp[t], a1 = rp[t + 1024];
  int hak = ha[k0];

  for (int k = k0; k < kend; ++k) {
    // stage row k from prefetched regs
    lds4[t] = a0;
    lds4[t + 1024] = a1;

    // issue ha-row loads (consumed after the gather phase)
    const float4* ra = (const float4*)(S + (size_t)hak * B);
    float4 b0 = ra[t], b1 = ra[t + 1024];
    if (k + 1 < kend) hak = ha[k + 1];

    __syncthreads();  // staging visible

    // issue next-row prefetch (consumed at next staging)
    if (k + 1 < kend) {
      const float4* rn = (const float4*)(S + (size_t)(k + 1) * B);
      a0 = rn[t];
      a1 = rn[t + 1024];
    }

    // own columns back from LDS (conflict-free b128), frees a-regs
    float4 v0 = lds4[t], v1 = lds4[t + 1024];
    const float vv[8] = {v0.x, v0.y, v0.z, v0.w, v1.x, v1.y, v1.z, v1.w};

    float g[8];
#pragma unroll
    for (int c = 0; c < 8; ++c) g[c] = lds[hti[c]];  // random gather, ~2-way
#pragma unroll
    for (int c = 0; c < 8; ++c) {
      dacc[c] += vv[c] * g[c];
      sacc[c] += vv[c] * vv[c];
    }

    // row-dot with ha row (b regs arrive ~here) + rowsq
    float d = vv[0] * b0.x + vv[1] * b0.y + vv[2] * b0.z + vv[3] * b0.w
            + vv[4] * b1.x + vv[5] * b1.y + vv[6] * b1.z + vv[7] * b1.w;
    float s = vv[0] * vv[0] + vv[1] * vv[1] + vv[2] * vv[2] + vv[3] * vv[3]
            + vv[4] * vv[4] + vv[5] * vv[5] + vv[6] * vv[6] + vv[7] * vv[7];
#pragma unroll
    for (int o = 32; o > 0; o >>= 1) {
      d += __shfl_down(d, o, 64);
      s += __shfl_down(s, o, 64);
    }
    float* redk = red + ((k & 1) << 5);
    if ((t & 63) == 0) { redk[t >> 6] = d; redk[16 + (t >> 6)] = s; }

    __syncthreads();  // red visible + LDS safe to overwrite next iter

    if (t == 0) {
      float dd = 0.f, ss = 0.f;
#pragma unroll
      for (int w = 0; w < 16; ++w) { dd += redk[w]; ss += redk[16 + w]; }
      dot_row[k] = dd;
      rowsq[k] = ss;
    }
  }

#pragma unroll
  for (int c = 0; c < 4; ++c) {
    atomicAdd(&dot_col[4 * t + c], dacc[c]);
    atomicAdd(&colsq[4 * t + c], sacc[c]);
    atomicAdd(&dot_col[4096 + 4 * t + c], dacc[4 + c]);
    atomicAdd(&colsq[4096 + 4 * t + c], sacc[4 + c]);
  }
}

// ---------------------------------------------------------------------------
// Finalize: single block; gathers 3 scalar S elements per i, assembles
// triplet + consistency terms, block-reduces to the 3 outputs.
// ---------------------------------------------------------------------------
__global__ __launch_bounds__(1024) void finalize_kernel(
    const float* __restrict__ S, const unsigned char* __restrict__ pmask,
    const int* __restrict__ ha, const int* __restrict__ ht,
    const float* __restrict__ dot_col, const float* __restrict__ colsq,
    const float* __restrict__ dot_row, const float* __restrict__ rowsq,
    float* __restrict__ out, int B) {
  const int t = threadIdx.x;
  float cnt = 0.f, tripS = 0.f, consS = 0.f;

  for (int i = t; i < B; i += 1024) {
    const float m = pmask[(size_t)i * B + i] ? 1.f : 0.f;
    const int a = ha[i];
    const int x = ht[i];
    const float pos = S[(size_t)i * B + i];
    const float an  = S[(size_t)a * B + i];
    const float tn  = S[(size_t)i * B + x];
    const float trip = fmaxf(MARGIN - pos + tn, 0.f) + fmaxf(MARGIN - pos + an, 0.f);

    const float cosA = dot_row[i] / fmaxf(sqrtf(rowsq[i]) * sqrtf(rowsq[a]), COS_EPS);
    const float cosT = dot_col[i] / fmaxf(sqrtf(colsq[i]) * sqrtf(colsq[x]), COS_EPS);
    const float cons = fmaxf(fabsf(cosA - cosT), 0.f);  // SIGMA_MARGIN = 0

    cnt += m;
    tripS += trip * m;
    consS += cons * m;
  }

  __shared__ float red[48];
#pragma unroll
  for (int o = 32; o > 0; o >>= 1) {
    cnt   += __shfl_down(cnt, o, 64);
    tripS += __shfl_down(tripS, o, 64);
    consS += __shfl_down(consS, o, 64);
  }
  const int wid = t >> 6, lane = t & 63;
  if (lane == 0) { red[wid] = cnt; red[16 + wid] = tripS; red[32 + wid] = consS; }
  __syncthreads();
  if (t == 0) {
    float c = 0.f, tp = 0.f, cs = 0.f;
    for (int w = 0; w < 16; ++w) { c += red[w]; tp += red[16 + w]; cs += red[32 + w]; }
    c = fmaxf(c, 1.f);
    const float triplet = tp / c;
    const float consistency = cs / c;
    out[0] = triplet + LAMBDA_CONSISTENCY * consistency;
    out[1] = triplet;
    out[2] = consistency;
  }
}

extern "C" void kernel_launch(void* const* d_in, const int* in_sizes, int n_in,
                              void* d_out, int out_size, void* d_ws, size_t ws_size,
                              hipStream_t stream) {
  const float* S = (const float*)d_in[0];
  const unsigned char* pmask = (const unsigned char*)d_in[1];  // jnp bool -> 1 byte
  const int* ha = (const int*)d_in[2];
  const int* ht = (const int*)d_in[3];
  const int B = in_sizes[2];  // 8192

  float* ws = (float*)d_ws;
  float* dot_col = ws;
  float* colsq   = ws + B;
  float* dot_row = ws + 2 * B;
  float* rowsq   = ws + 3 * B;

  // zero only the atomically-accumulated arrays
  hipMemsetAsync(ws, 0, (size_t)2 * B * sizeof(float), stream);

  const int blocks = 512;  // 16 rows/block at B=8192; 2 blocks/CU
  fused_pass_kernel<<<blocks, 1024, (B + 64) * sizeof(float), stream>>>(
      S, ha, ht, dot_col, colsq, dot_row, rowsq, B, B / blocks);

  finalize_kernel<<<1, 1024, 0, stream>>>(
      S, pmask, ha, ht, dot_col, colsq, dot_row, rowsq, (float*)d_out, B);
}

// Round 4
// 305.783 us; speedup vs baseline: 1.0692x; 1.0692x over previous
//
#include <hip/hip_runtime.h>

#define MARGIN 0.2f
#define LAMBDA_CONSISTENCY 0.1f
#define COS_EPS 1e-8f

// ---------------------------------------------------------------------------
// Fused pass, software-pipelined, double-buffered staging, ONE barrier/row.
// Each block owns a contiguous chunk of rows. Register pipeline per iter k:
//   cur regs  = row k own values (cols 4t..4t+3, 4096+4t..+3)
//   b regs    = row ha[k] values          (issued iter k-1)
//   a regs    = row k+1 values            (issued iter k-1)
// Body: stage a -> buf[(k+1)&1] (no alias with gather buf[k&1]);
//       gather ht from buf[k&1]; dot_col/colsq from cur regs;
//       d = cur.b, s = cur.cur -> wave reduce -> red[k&1];
//       rotate cur<-a; issue next b (ha[k+1]) and next a (k+2);
//       __syncthreads(); t0 writes dot_row[k], rowsq[k].
// S streamed from HBM once coalesced + ha-rows (L2/L3-friendly).
// NOTE: launch_bounds min-waves=4 (VGPR cap 128) — round 3 proved 8 (cap 64)
// forces spills (WRITE_SIZE 273 MB of scratch traffic).
// ---------------------------------------------------------------------------
__global__ __launch_bounds__(1024, 4) void fused_pass_kernel(
    const float* __restrict__ S, const int* __restrict__ ha,
    const int* __restrict__ ht,
    float* __restrict__ dot_col, float* __restrict__ colsq,
    float* __restrict__ dot_row, float* __restrict__ rowsq,
    int B, int rows_per_block) {
  extern __shared__ float lds[];  // 2*B staging (double buffer) + 64 red
  float* red = lds + 2 * B;       // red[2][32]
  const int t = threadIdx.x;

  int4 h0 = ((const int4*)ht)[t];
  int4 h1 = ((const int4*)ht)[t + 1024];
  const int hti[8] = {h0.x, h0.y, h0.z, h0.w, h1.x, h1.y, h1.z, h1.w};

  float dacc[8] = {0.f, 0.f, 0.f, 0.f, 0.f, 0.f, 0.f, 0.f};
  float sacc[8] = {0.f, 0.f, 0.f, 0.f, 0.f, 0.f, 0.f, 0.f};

  const int k0 = blockIdx.x * rows_per_block;
  const int kend = k0 + rows_per_block;

  // prologue: row k0 -> buf0 + cur regs; issue b(ha[k0]) and a(row k0+1)
  const float4* r0 = (const float4*)(S + (size_t)k0 * B);
  float4 c0 = r0[t], c1 = r0[t + 1024];
  ((float4*)lds)[t] = c0;
  ((float4*)lds)[t + 1024] = c1;
  int hak = ha[k0];
  const float4* rb = (const float4*)(S + (size_t)hak * B);
  float4 b0 = rb[t], b1 = rb[t + 1024];
  int hak1 = (k0 + 1 < kend) ? ha[k0 + 1] : 0;
  float4 a0 = c0, a1 = c1;
  if (k0 + 1 < kend) {
    const float4* rn = (const float4*)(S + (size_t)(k0 + 1) * B);
    a0 = rn[t];
    a1 = rn[t + 1024];
  }
  __syncthreads();  // buf0 visible

  for (int k = k0; k < kend; ++k) {
    float* cb = lds + ((k & 1) ? B : 0);   // gather source (row k)
    float* nb = lds + ((k & 1) ? 0 : B);   // staging target (row k+1)

    if (k + 1 < kend) {                    // no alias with cb: no barrier
      ((float4*)nb)[t] = a0;
      ((float4*)nb)[t + 1024] = a1;
    }

    const float cv[8] = {c0.x, c0.y, c0.z, c0.w, c1.x, c1.y, c1.z, c1.w};
    float g[8];
#pragma unroll
    for (int c = 0; c < 8; ++c) g[c] = cb[hti[c]];  // random gather, ~2-way
#pragma unroll
    for (int c = 0; c < 8; ++c) {
      dacc[c] += cv[c] * g[c];
      sacc[c] += cv[c] * cv[c];
    }

    float d = cv[0] * b0.x + cv[1] * b0.y + cv[2] * b0.z + cv[3] * b0.w
            + cv[4] * b1.x + cv[5] * b1.y + cv[6] * b1.z + cv[7] * b1.w;
    float s = cv[0] * cv[0] + cv[1] * cv[1] + cv[2] * cv[2] + cv[3] * cv[3]
            + cv[4] * cv[4] + cv[5] * cv[5] + cv[6] * cv[6] + cv[7] * cv[7];

    // rotate pipeline: cur <- a, then reissue b and a for iter k+1
    c0 = a0;
    c1 = a1;
    if (k + 1 < kend) {
      const float4* rb2 = (const float4*)(S + (size_t)hak1 * B);
      b0 = rb2[t];
      b1 = rb2[t + 1024];
      hak1 = (k + 2 < kend) ? ha[k + 2] : 0;
    }
    if (k + 2 < kend) {
      const float4* rn = (const float4*)(S + (size_t)(k + 2) * B);
      a0 = rn[t];
      a1 = rn[t + 1024];
    }

#pragma unroll
    for (int o = 32; o > 0; o >>= 1) {
      d += __shfl_down(d, o, 64);
      s += __shfl_down(s, o, 64);
    }
    float* redk = red + ((k & 1) << 5);
    if ((t & 63) == 0) { redk[t >> 6] = d; redk[16 + (t >> 6)] = s; }

    __syncthreads();  // staged row k+1 + red visible

    if (t == 0) {
      float dd = 0.f, ss = 0.f;
#pragma unroll
      for (int w = 0; w < 16; ++w) { dd += redk[w]; ss += redk[16 + w]; }
      dot_row[k] = dd;
      rowsq[k] = ss;
    }
  }

#pragma unroll
  for (int c = 0; c < 4; ++c) {
    atomicAdd(&dot_col[4 * t + c], dacc[c]);
    atomicAdd(&colsq[4 * t + c], sacc[c]);
    atomicAdd(&dot_col[4096 + 4 * t + c], dacc[4 + c]);
    atomicAdd(&colsq[4096 + 4 * t + c], sacc[4 + c]);
  }
}

// ---------------------------------------------------------------------------
// Finalize: single block; gathers 3 scalar S elements per i, assembles
// triplet + consistency terms, block-reduces to the 3 outputs.
// ---------------------------------------------------------------------------
__global__ __launch_bounds__(1024) void finalize_kernel(
    const float* __restrict__ S, const unsigned char* __restrict__ pmask,
    const int* __restrict__ ha, const int* __restrict__ ht,
    const float* __restrict__ dot_col, const float* __restrict__ colsq,
    const float* __restrict__ dot_row, const float* __restrict__ rowsq,
    float* __restrict__ out, int B) {
  const int t = threadIdx.x;
  float cnt = 0.f, tripS = 0.f, consS = 0.f;

#pragma unroll 8
  for (int i = t; i < B; i += 1024) {
    const float m = pmask[(size_t)i * B + i] ? 1.f : 0.f;
    const int a = ha[i];
    const int x = ht[i];
    const float pos = S[(size_t)i * B + i];
    const float an  = S[(size_t)a * B + i];
    const float tn  = S[(size_t)i * B + x];
    const float trip = fmaxf(MARGIN - pos + tn, 0.f) + fmaxf(MARGIN - pos + an, 0.f);

    const float cosA = dot_row[i] / fmaxf(sqrtf(rowsq[i]) * sqrtf(rowsq[a]), COS_EPS);
    const float cosT = dot_col[i] / fmaxf(sqrtf(colsq[i]) * sqrtf(colsq[x]), COS_EPS);
    const float cons = fmaxf(fabsf(cosA - cosT), 0.f);  // SIGMA_MARGIN = 0

    cnt += m;
    tripS += trip * m;
    consS += cons * m;
  }

  __shared__ float red[48];
#pragma unroll
  for (int o = 32; o > 0; o >>= 1) {
    cnt   += __shfl_down(cnt, o, 64);
    tripS += __shfl_down(tripS, o, 64);
    consS += __shfl_down(consS, o, 64);
  }
  const int wid = t >> 6, lane = t & 63;
  if (lane == 0) { red[wid] = cnt; red[16 + wid] = tripS; red[32 + wid] = consS; }
  __syncthreads();
  if (t == 0) {
    float c = 0.f, tp = 0.f, cs = 0.f;
    for (int w = 0; w < 16; ++w) { c += red[w]; tp += red[16 + w]; cs += red[32 + w]; }
    c = fmaxf(c, 1.f);
    const float triplet = tp / c;
    const float consistency = cs / c;
    out[0] = triplet + LAMBDA_CONSISTENCY * consistency;
    out[1] = triplet;
    out[2] = consistency;
  }
}

extern "C" void kernel_launch(void* const* d_in, const int* in_sizes, int n_in,
                              void* d_out, int out_size, void* d_ws, size_t ws_size,
                              hipStream_t stream) {
  const float* S = (const float*)d_in[0];
  const unsigned char* pmask = (const unsigned char*)d_in[1];  // jnp bool -> 1 byte
  const int* ha = (const int*)d_in[2];
  const int* ht = (const int*)d_in[3];
  const int B = in_sizes[2];  // 8192

  float* ws = (float*)d_ws;
  float* dot_col = ws;
  float* colsq   = ws + B;
  float* dot_row = ws + 2 * B;
  float* rowsq   = ws + 3 * B;

  // zero only the atomically-accumulated arrays
  hipMemsetAsync(ws, 0, (size_t)2 * B * sizeof(float), stream);

  const int blocks = 512;  // 16 rows/block at B=8192
  fused_pass_kernel<<<blocks, 1024, (2 * B + 64) * sizeof(float), stream>>>(
      S, ha, ht, dot_col, colsq, dot_row, rowsq, B, B / blocks);

  finalize_kernel<<<1, 1024, 0, stream>>>(
      S, pmask, ha, ht, dot_col, colsq, dot_row, rowsq, (float*)d_out, B);
}

// Round 5
// 246.906 us; speedup vs baseline: 1.3242x; 1.2385x over previous
//
#include <hip/hip_runtime.h>

#define MARGIN 0.2f
#define LAMBDA_CONSISTENCY 0.1f
#define COS_EPS 1e-8f

#define B_DIM 8192
#define RPB   32            // rows per block
#define NBLK  (B_DIM / RPB) // 256 blocks = 1 per CU
#define NTHR  1024

// async global->LDS, 16B per lane. LDS dest is wave-uniform base + lane*16
// (m104/m108); global source is per-lane.
__device__ __forceinline__ void gload16(const float* g, float* l) {
  __builtin_amdgcn_global_load_lds(
      (const __attribute__((address_space(1))) void*)g,
      (__attribute__((address_space(3))) void*)l, 16, 0, 0);
}

// wave w stages its 2KB slice of one 32KB row: 2 instructions x 1KB
__device__ __forceinline__ void stage_row(const float* rowg, float* buf,
                                          int w, int lane) {
  gload16(rowg + w * 512 + lane * 4,       buf + w * 512);
  gload16(rowg + w * 512 + 256 + lane * 4, buf + w * 512 + 256);
}

// ---------------------------------------------------------------------------
// Fused pass, LDS-DMA pipelined. Block owns 32 rows. Double-buffered 32KB
// row buffers for own-row (K) and ha-row (H): 128KB LDS (1 block/CU).
// Per iteration: issue 4 gload_lds for row-pair k+1 -> parity p^1;
// s_waitcnt vmcnt(4) (row-k loads done, k+1 stays in flight); raw s_barrier;
// compute row k from LDS (own cols via ds_read_b128, ht gather, ha dot);
// wave-reduce d,s -> lane0 atomicAdd; fence; s_barrier (reuse guard).
// No destination registers for staging => compiler cannot sink the prefetch
// (round-3/4 failure mode). vmcnt queue per wave per iter, in order:
// [L(k+1) x4, atomics x2, L(k+2) x4] -> vmcnt(4) certifies L(k+1)+atomics.
// ---------------------------------------------------------------------------
__global__ __launch_bounds__(1024, 4) void fused_pass_kernel(
    const float* __restrict__ S, const int* __restrict__ ha,
    const int* __restrict__ ht,
    float* __restrict__ dot_col, float* __restrict__ colsq,
    float* __restrict__ dot_row, float* __restrict__ rowsq) {
  __shared__ __align__(16) float bufK[2][B_DIM];  // own rows
  __shared__ __align__(16) float bufH[2][B_DIM];  // ha rows
  const int t = threadIdx.x;
  const int w = t >> 6, lane = t & 63;

  // thread t owns cols 4t..4t+3 and 4096+4t..4096+4t+3
  int4 h0 = ((const int4*)ht)[t];
  int4 h1 = ((const int4*)ht)[t + 1024];
  const int hti[8] = {h0.x, h0.y, h0.z, h0.w, h1.x, h1.y, h1.z, h1.w};

  float dacc[8] = {0.f, 0.f, 0.f, 0.f, 0.f, 0.f, 0.f, 0.f};
  float sacc[8] = {0.f, 0.f, 0.f, 0.f, 0.f, 0.f, 0.f, 0.f};

  const int k0 = blockIdx.x * RPB;

  // prologue: stage row k0 pair into parity 0, drain, sync
  stage_row(S + (size_t)k0 * B_DIM, &bufK[0][0], w, lane);
  stage_row(S + (size_t)ha[k0] * B_DIM, &bufH[0][0], w, lane);
  asm volatile("s_waitcnt vmcnt(0)" ::: "memory");
  __builtin_amdgcn_s_barrier();
  asm volatile("" ::: "memory");

  for (int kk = 0; kk < RPB; ++kk) {
    const int k = k0 + kk;
    const int p = kk & 1;

    if (kk + 1 < RPB) {  // issue next row-pair into the other parity
      stage_row(S + (size_t)(k + 1) * B_DIM, &bufK[p ^ 1][0], w, lane);
      stage_row(S + (size_t)ha[k + 1] * B_DIM, &bufH[p ^ 1][0], w, lane);
      asm volatile("s_waitcnt vmcnt(4)" ::: "memory");  // row k ready
    } else {
      asm volatile("s_waitcnt vmcnt(0)" ::: "memory");
    }
    __builtin_amdgcn_s_barrier();      // all waves' slices of row k staged
    asm volatile("" ::: "memory");     // fence: no ds_read hoists above

    const float4* bk4 = (const float4*)bufK[p];
    const float4* bh4 = (const float4*)bufH[p];
    float4 v0 = bk4[t], v1 = bk4[t + 1024];
    float4 b0 = bh4[t], b1 = bh4[t + 1024];
    const float* bk = bufK[p];
    const float vv[8] = {v0.x, v0.y, v0.z, v0.w, v1.x, v1.y, v1.z, v1.w};
    const float bb[8] = {b0.x, b0.y, b0.z, b0.w, b1.x, b1.y, b1.z, b1.w};

    float g[8];
#pragma unroll
    for (int c = 0; c < 8; ++c) g[c] = bk[hti[c]];  // random gather, ~2-4 way

    float d = 0.f, s = 0.f;
#pragma unroll
    for (int c = 0; c < 8; ++c) {
      dacc[c] += vv[c] * g[c];
      sacc[c] += vv[c] * vv[c];
      d += vv[c] * bb[c];
      s += vv[c] * vv[c];
    }
#pragma unroll
    for (int o = 32; o > 0; o >>= 1) {
      d += __shfl_down(d, o, 64);
      s += __shfl_down(s, o, 64);
    }
    if (lane == 0) {  // issued BEFORE next stage: keeps vmcnt queue in order
      atomicAdd(&dot_row[k], d);
      atomicAdd(&rowsq[k], s);
    }
    asm volatile("" ::: "memory");   // fence: no ds_read sinks below
    __builtin_amdgcn_s_barrier();    // reuse guard for parity p buffers
  }

#pragma unroll
  for (int c = 0; c < 4; ++c) {
    atomicAdd(&dot_col[4 * t + c], dacc[c]);
    atomicAdd(&colsq[4 * t + c], sacc[c]);
    atomicAdd(&dot_col[4096 + 4 * t + c], dacc[4 + c]);
    atomicAdd(&colsq[4096 + 4 * t + c], sacc[4 + c]);
  }
}

// ---------------------------------------------------------------------------
// Finalize: single block; gathers 3 scalar S elements per i, assembles
// triplet + consistency terms, block-reduces to the 3 outputs.
// ---------------------------------------------------------------------------
__global__ __launch_bounds__(1024) void finalize_kernel(
    const float* __restrict__ S, const unsigned char* __restrict__ pmask,
    const int* __restrict__ ha, const int* __restrict__ ht,
    const float* __restrict__ dot_col, const float* __restrict__ colsq,
    const float* __restrict__ dot_row, const float* __restrict__ rowsq,
    float* __restrict__ out, int B) {
  const int t = threadIdx.x;
  float cnt = 0.f, tripS = 0.f, consS = 0.f;

#pragma unroll 8
  for (int i = t; i < B; i += 1024) {
    const float m = pmask[(size_t)i * B + i] ? 1.f : 0.f;
    const int a = ha[i];
    const int x = ht[i];
    const float pos = S[(size_t)i * B + i];
    const float an  = S[(size_t)a * B + i];
    const float tn  = S[(size_t)i * B + x];
    const float trip = fmaxf(MARGIN - pos + tn, 0.f) + fmaxf(MARGIN - pos + an, 0.f);

    const float cosA = dot_row[i] / fmaxf(sqrtf(rowsq[i]) * sqrtf(rowsq[a]), COS_EPS);
    const float cosT = dot_col[i] / fmaxf(sqrtf(colsq[i]) * sqrtf(colsq[x]), COS_EPS);
    const float cons = fmaxf(fabsf(cosA - cosT), 0.f);  // SIGMA_MARGIN = 0

    cnt += m;
    tripS += trip * m;
    consS += cons * m;
  }

  __shared__ float red[48];
#pragma unroll
  for (int o = 32; o > 0; o >>= 1) {
    cnt   += __shfl_down(cnt, o, 64);
    tripS += __shfl_down(tripS, o, 64);
    consS += __shfl_down(consS, o, 64);
  }
  const int wid = t >> 6, lane = t & 63;
  if (lane == 0) { red[wid] = cnt; red[16 + wid] = tripS; red[32 + wid] = consS; }
  __syncthreads();
  if (t == 0) {
    float c = 0.f, tp = 0.f, cs = 0.f;
    for (int w = 0; w < 16; ++w) { c += red[w]; tp += red[16 + w]; cs += red[32 + w]; }
    c = fmaxf(c, 1.f);
    const float triplet = tp / c;
    const float consistency = cs / c;
    out[0] = triplet + LAMBDA_CONSISTENCY * consistency;
    out[1] = triplet;
    out[2] = consistency;
  }
}

extern "C" void kernel_launch(void* const* d_in, const int* in_sizes, int n_in,
                              void* d_out, int out_size, void* d_ws, size_t ws_size,
                              hipStream_t stream) {
  const float* S = (const float*)d_in[0];
  const unsigned char* pmask = (const unsigned char*)d_in[1];  // jnp bool -> 1 byte
  const int* ha = (const int*)d_in[2];
  const int* ht = (const int*)d_in[3];
  const int B = in_sizes[2];  // 8192

  float* ws = (float*)d_ws;
  float* dot_col = ws;
  float* colsq   = ws + B;
  float* dot_row = ws + 2 * B;
  float* rowsq   = ws + 3 * B;

  // all four arrays are atomic-accumulated now -> zero them
  hipMemsetAsync(ws, 0, (size_t)4 * B * sizeof(float), stream);

  fused_pass_kernel<<<NBLK, NTHR, 0, stream>>>(
      S, ha, ht, dot_col, colsq, dot_row, rowsq);

  finalize_kernel<<<1, 1024, 0, stream>>>(
      S, pmask, ha, ht, dot_col, colsq, dot_row, rowsq, (float*)d_out, B);
}